// Round 1
// baseline (620.882 us; speedup 1.0000x reference)
//
#include <hip/hip_runtime.h>
#include <stdint.h>

typedef __attribute__((ext_vector_type(8))) short bf16x8;
typedef __attribute__((ext_vector_type(4))) float f32x4;
typedef __attribute__((ext_vector_type(4))) unsigned short u16x4;

#define LOG2E 1.44269504088896340736f
#define SCALE 0.0625f

__device__ __forceinline__ unsigned short f32_bf16(float f) {
  unsigned int u = __float_as_uint(f);
  u += 0x7fffu + ((u >> 16) & 1u);
  return (unsigned short)(u >> 16);
}
__device__ __forceinline__ float bf16_f32(unsigned short h) {
  return __uint_as_float(((unsigned int)h) << 16);
}

__device__ __forceinline__ void gload16(const unsigned short* g, unsigned short* l) {
  __builtin_amdgcn_global_load_lds((const __attribute__((address_space(1))) void*)g,
                                   (__attribute__((address_space(3))) void*)l, 16, 0, 0);
}

// ---------------- cast f32 -> bf16 (vectorized) ----------------
__global__ void cast_kernel(const float* __restrict__ in, unsigned short* __restrict__ out, int n4) {
  int i = blockIdx.x * blockDim.x + threadIdx.x;
  if (i >= n4) return;
  const float4 v = ((const float4*)in)[i];
  u16x4 o;
  o[0] = f32_bf16(v.x); o[1] = f32_bf16(v.y); o[2] = f32_bf16(v.z); o[3] = f32_bf16(v.w);
  ((u16x4*)out)[i] = o;
}

// ---------------- GEMM: C[M][N] = A[M][K] * B[N][K]^T (bf16 in, f32 acc) ----------------
template<int OUTF32>
__global__ __launch_bounds__(256) void gemm_nt(const unsigned short* __restrict__ A,
                                               const unsigned short* __restrict__ B,
                                               void* __restrict__ Cp,
                                               int M, int N, int K) {
  __shared__ unsigned short As[128 * 32];
  __shared__ unsigned short Bs[128 * 32];
  const int t = threadIdx.x;
  const int lane = t & 63;
  const int wave = t >> 6;
  const int wr = (wave >> 1) * 64;
  const int wc = (wave & 1) * 64;
  const long m0 = (long)blockIdx.y * 128;
  const long n0 = (long)blockIdx.x * 128;
  const int l15 = lane & 15, lg = lane >> 4;

  f32x4 acc[4][4];
#pragma unroll
  for (int m = 0; m < 4; ++m)
#pragma unroll
    for (int n = 0; n < 4; ++n) acc[m][n] = (f32x4){0.f, 0.f, 0.f, 0.f};

  const int srow = t >> 2;
  const int scol = (t & 3) * 8;
  const unsigned short* Ag = A + (m0 + srow) * (long)K + scol;
  const unsigned short* Bg = B + (n0 + srow) * (long)K + scol;

  for (int k0 = 0; k0 < K; k0 += 32) {
    gload16(Ag + k0, &As[t * 8]);
    gload16(Ag + (long)64 * K + k0, &As[2048 + t * 8]);
    gload16(Bg + k0, &Bs[t * 8]);
    gload16(Bg + (long)64 * K + k0, &Bs[2048 + t * 8]);
    __syncthreads();
    bf16x8 af[4], bfr[4];
#pragma unroll
    for (int m = 0; m < 4; ++m) af[m] = *(const bf16x8*)&As[(wr + m * 16 + l15) * 32 + lg * 8];
#pragma unroll
    for (int n = 0; n < 4; ++n) bfr[n] = *(const bf16x8*)&Bs[(wc + n * 16 + l15) * 32 + lg * 8];
#pragma unroll
    for (int m = 0; m < 4; ++m)
#pragma unroll
      for (int n = 0; n < 4; ++n)
        acc[m][n] = __builtin_amdgcn_mfma_f32_16x16x32_bf16(af[m], bfr[n], acc[m][n], 0, 0, 0);
    __syncthreads();
  }

#pragma unroll
  for (int m = 0; m < 4; ++m)
#pragma unroll
    for (int n = 0; n < 4; ++n)
#pragma unroll
      for (int r = 0; r < 4; ++r) {
        long row = m0 + wr + m * 16 + lg * 4 + r;
        long col = n0 + wc + n * 16 + l15;
        if (OUTF32)
          ((float*)Cp)[row * N + col] = acc[m][n][r];
        else
          ((unsigned short*)Cp)[row * N + col] = f32_bf16(acc[m][n][r]);
      }
}

// ---------------- RoPE in-place on bf16 Q and K ----------------
__global__ void rope_kernel(unsigned short* __restrict__ Q, unsigned short* __restrict__ Kb,
                            const int* __restrict__ pos_ids, int nQ, int nTot) {
  int tid = blockIdx.x * blockDim.x + threadIdx.x;
  if (tid >= nTot) return;
  if (tid < nQ) {
    int d = tid & 127;
    int rest = tid >> 7;
    int h = rest & 7; rest >>= 3;
    int s = rest & 2047;
    int b = rest >> 11;
    long base = ((long)(b * 2048 + s)) * 2048 + h * 256 + d;
    float pos = (float)pos_ids[b * 2048 + s];
    // inv_freq = 10000^(-d/128) = 2^(-d * log2(10000)/128)
    float f = pos * exp2f(-(float)d * 0.1038102529652328f);
    float c, sn;
    sincosf(f, &sn, &c);
    float q1 = bf16_f32(Q[base]), q2 = bf16_f32(Q[base + 128]);
    Q[base] = f32_bf16(q1 * c - q2 * sn);
    Q[base + 128] = f32_bf16(q2 * c + q1 * sn);
  } else {
    int tid2 = tid - nQ;
    int d = tid2 & 127;
    int rest = tid2 >> 7;
    int s = rest & 2047;
    int b = rest >> 11;
    long base = ((long)(b * 2048 + s)) * 256 + d;
    float pos = (float)pos_ids[b * 2048 + s];
    float f = pos * exp2f(-(float)d * 0.1038102529652328f);
    float c, sn;
    sincosf(f, &sn, &c);
    float q1 = bf16_f32(Kb[base]), q2 = bf16_f32(Kb[base + 128]);
    Kb[base] = f32_bf16(q1 * c - q2 * sn);
    Kb[base + 128] = f32_bf16(q2 * c + q1 * sn);
  }
}

// ---------------- V transpose: Vt[b][d][s] = V[b][s][d] ----------------
__global__ void transpose_v(const unsigned short* __restrict__ V, unsigned short* __restrict__ Vt, int n) {
  int tid = blockIdx.x * blockDim.x + threadIdx.x;
  if (tid >= n) return;
  int s = tid & 2047;
  int d = (tid >> 11) & 255;
  int b = tid >> 19;
  Vt[tid] = V[((long)(b * 2048 + s)) * 256 + d];
}

// ---------------- flash attention, sliding-window causal, GQA (KVH=1) ----------------
__global__ __launch_bounds__(256) void attn_kernel(const unsigned short* __restrict__ Q,
                                                   const unsigned short* __restrict__ Kb,
                                                   const unsigned short* __restrict__ Vt,
                                                   unsigned short* __restrict__ O) {
  __shared__ __align__(16) unsigned short Plds[4][16 * 40];  // per-wave P buffer, padded stride 40
  const int t = threadIdx.x, lane = t & 63, wave = t >> 6;
  const int qb = blockIdx.x, h = blockIdx.y, b = blockIdx.z;
  const int q0 = qb * 64;
  const int qw = q0 + wave * 16;
  const int l15 = lane & 15, lg = lane >> 4;

  // Q fragments: A-layout row = lane&15, k = (lane>>4)*8 + e, 8 chunks over HD=256
  bf16x8 qf[8];
  {
    const unsigned short* qptr = Q + ((long)(b * 2048 + qw + l15)) * 2048 + h * 256 + lg * 8;
#pragma unroll
    for (int c = 0; c < 8; ++c) qf[c] = *(const bf16x8*)(qptr + c * 32);
  }

  f32x4 oacc[16];
#pragma unroll
  for (int dt = 0; dt < 16; ++dt) oacc[dt] = (f32x4){0.f, 0.f, 0.f, 0.f};
  float mrun[4], lrun[4];
  int qrow[4];
#pragma unroll
  for (int r = 0; r < 4; ++r) { mrun[r] = -3e38f; lrun[r] = 0.f; qrow[r] = qw + lg * 4 + r; }

  const unsigned short* Kbase = Kb + ((long)b * 2048) * 256;
  const unsigned short* Vbase = Vt + (long)b * 256 * 2048;

  int ks0 = q0 - 1023;
  if (ks0 < 0) ks0 = 0;
  ks0 &= ~31;

  for (int ks = ks0; ks < q0 + 64; ks += 32) {
    // --- QK^T: two 16-key tiles ---
    f32x4 s0 = (f32x4){0.f, 0.f, 0.f, 0.f};
    f32x4 s1 = (f32x4){0.f, 0.f, 0.f, 0.f};
    const unsigned short* kp0 = Kbase + (long)(ks + l15) * 256 + lg * 8;
    const unsigned short* kp1 = kp0 + 16 * 256;
#pragma unroll
    for (int c = 0; c < 8; ++c) {
      bf16x8 k0f = *(const bf16x8*)(kp0 + c * 32);
      bf16x8 k1f = *(const bf16x8*)(kp1 + c * 32);
      s0 = __builtin_amdgcn_mfma_f32_16x16x32_bf16(qf[c], k0f, s0, 0, 0, 0);
      s1 = __builtin_amdgcn_mfma_f32_16x16x32_bf16(qf[c], k1f, s1, 0, 0, 0);
    }

    // --- mask + online softmax ---
    const int key0 = ks + l15, key1 = key0 + 16;
    float p0[4], p1[4], alpha[4];
#pragma unroll
    for (int r = 0; r < 4; ++r) {
      float v0 = s0[r] * SCALE, v1 = s1[r] * SCALE;
      bool val0 = (key0 <= qrow[r]) && (key0 > qrow[r] - 1024);
      bool val1 = (key1 <= qrow[r]) && (key1 > qrow[r] - 1024);
      v0 = val0 ? v0 : -3e38f;
      v1 = val1 ? v1 : -3e38f;
      float mx = fmaxf(v0, v1);
      mx = fmaxf(mx, __shfl_xor(mx, 1, 16));
      mx = fmaxf(mx, __shfl_xor(mx, 2, 16));
      mx = fmaxf(mx, __shfl_xor(mx, 4, 16));
      mx = fmaxf(mx, __shfl_xor(mx, 8, 16));
      float mnew = fmaxf(mrun[r], mx);
      alpha[r] = exp2f((mrun[r] - mnew) * LOG2E);
      mrun[r] = mnew;
      p0[r] = val0 ? exp2f((v0 - mnew) * LOG2E) : 0.f;
      p1[r] = val1 ? exp2f((v1 - mnew) * LOG2E) : 0.f;
      float sum = p0[r] + p1[r];
      sum += __shfl_xor(sum, 1, 16);
      sum += __shfl_xor(sum, 2, 16);
      sum += __shfl_xor(sum, 4, 16);
      sum += __shfl_xor(sum, 8, 16);
      lrun[r] = lrun[r] * alpha[r] + sum;
    }

    // --- rescale O ---
#pragma unroll
    for (int dt = 0; dt < 16; ++dt)
#pragma unroll
      for (int r = 0; r < 4; ++r) oacc[dt][r] *= alpha[r];

    // --- P (D-layout) -> LDS -> A-frag layout ---
    unsigned short* pw = &Plds[wave][0];
#pragma unroll
    for (int r = 0; r < 4; ++r) {
      int row = lg * 4 + r;
      pw[row * 40 + l15] = f32_bf16(p0[r]);
      pw[row * 40 + 16 + l15] = f32_bf16(p1[r]);
    }
    __syncthreads();
    bf16x8 pa = *(const bf16x8*)&pw[l15 * 40 + lg * 8];

    // --- PV: 16 dim-tiles, B-frags from Vt (contiguous along keys) ---
    const unsigned short* vp = Vbase + (long)l15 * 2048 + ks + lg * 8;
#pragma unroll
    for (int dt = 0; dt < 16; ++dt) {
      bf16x8 vf = *(const bf16x8*)(vp + (long)dt * 16 * 2048);
      oacc[dt] = __builtin_amdgcn_mfma_f32_16x16x32_bf16(pa, vf, oacc[dt], 0, 0, 0);
    }
    __syncthreads();
  }

  // --- epilogue: normalize and write bf16 [b][s][h*256+d] ---
  const long obase = ((long)(b * 2048 + qw)) * 2048 + h * 256;
#pragma unroll
  for (int r = 0; r < 4; ++r) {
    float inv = 1.0f / lrun[r];
    int row = lg * 4 + r;
#pragma unroll
    for (int dt = 0; dt < 16; ++dt)
      O[obase + (long)row * 2048 + dt * 16 + l15] = f32_bf16(oacc[dt][r] * inv);
  }
}

// ---------------- launch ----------------
extern "C" void kernel_launch(void* const* d_in, const int* in_sizes, int n_in,
                              void* d_out, int out_size, void* d_ws, size_t ws_size,
                              hipStream_t stream) {
  const float* hidden = (const float*)d_in[0];
  // d_in[1]: attention_mask (pure causal; handled analytically)
  const int* pos_ids = (const int*)d_in[2];
  const float* Wq = (const float*)d_in[3];
  const float* Wk = (const float*)d_in[4];
  const float* Wv = (const float*)d_in[5];
  const float* Wo = (const float*)d_in[6];
  float* out = (float*)d_out;
  char* ws = (char*)d_ws;

  unsigned short* hid_bf = (unsigned short*)(ws);              // 16 MB (reused as attn out)
  unsigned short* wq_bf  = (unsigned short*)(ws + 16777216);   // 8 MB
  unsigned short* wk_bf  = (unsigned short*)(ws + 25165824);   // 1 MB
  unsigned short* wv_bf  = (unsigned short*)(ws + 26214400);   // 1 MB
  unsigned short* wo_bf  = (unsigned short*)(ws + 27262976);   // 8 MB
  unsigned short* qbuf   = (unsigned short*)(ws + 35651584);   // 16 MB
  unsigned short* kbuf   = (unsigned short*)(ws + 52428800);   // 2 MB
  unsigned short* vbuf   = (unsigned short*)(ws + 54525952);   // 2 MB
  unsigned short* vtbuf  = (unsigned short*)(ws + 56623104);   // 2 MB
  unsigned short* attno  = hid_bf;                             // alias: hidden dead after QKV GEMMs

  // casts
  {
    int n4;
    n4 = 8388608 / 4; cast_kernel<<<(n4 + 255) / 256, 256, 0, stream>>>(hidden, hid_bf, n4);
    n4 = 4194304 / 4; cast_kernel<<<(n4 + 255) / 256, 256, 0, stream>>>(Wq, wq_bf, n4);
    n4 = 524288 / 4;  cast_kernel<<<(n4 + 255) / 256, 256, 0, stream>>>(Wk, wk_bf, n4);
    n4 = 524288 / 4;  cast_kernel<<<(n4 + 255) / 256, 256, 0, stream>>>(Wv, wv_bf, n4);
    n4 = 4194304 / 4; cast_kernel<<<(n4 + 255) / 256, 256, 0, stream>>>(Wo, wo_bf, n4);
  }

  // projections
  gemm_nt<0><<<dim3(16, 32), 256, 0, stream>>>(hid_bf, wq_bf, qbuf, 4096, 2048, 2048);
  gemm_nt<0><<<dim3(2, 32), 256, 0, stream>>>(hid_bf, wk_bf, kbuf, 4096, 256, 2048);
  gemm_nt<0><<<dim3(2, 32), 256, 0, stream>>>(hid_bf, wv_bf, vbuf, 4096, 256, 2048);

  // rope on Q and K
  {
    int nQ = 2 * 2048 * 8 * 128;
    int nK = 2 * 2048 * 128;
    int nTot = nQ + nK;
    rope_kernel<<<(nTot + 255) / 256, 256, 0, stream>>>(qbuf, kbuf, pos_ids, nQ, nTot);
  }

  // V transpose
  transpose_v<<<(1048576 + 255) / 256, 256, 0, stream>>>(vbuf, vtbuf, 1048576);

  // attention
  attn_kernel<<<dim3(32, 8, 2), 256, 0, stream>>>(qbuf, kbuf, vtbuf, attno);

  // output projection (f32 out)
  gemm_nt<1><<<dim3(16, 32), 256, 0, stream>>>(attno, wo_bf, out, 4096, 2048, 2048);
}

// Round 2
// 360.381 us; speedup vs baseline: 1.7228x; 1.7228x over previous
//
#include <hip/hip_runtime.h>
#include <stdint.h>

typedef __attribute__((ext_vector_type(8))) short bf16x8;
typedef __attribute__((ext_vector_type(4))) float f32x4;
typedef __attribute__((ext_vector_type(4))) unsigned short u16x4;

#define LOG2E 1.44269504088896340736f
#define SCALE 0.0625f

__device__ __forceinline__ unsigned short f32_bf16(float f) {
  unsigned int u = __float_as_uint(f);
  u += 0x7fffu + ((u >> 16) & 1u);
  return (unsigned short)(u >> 16);
}
__device__ __forceinline__ float bf16_f32(unsigned short h) {
  return __uint_as_float(((unsigned int)h) << 16);
}

__device__ __forceinline__ void gload16(const unsigned short* g, unsigned short* l) {
  __builtin_amdgcn_global_load_lds((const __attribute__((address_space(1))) void*)g,
                                   (__attribute__((address_space(3))) void*)l, 16, 0, 0);
}

// ---------------- cast f32 -> bf16 (vectorized) ----------------
__global__ void cast_kernel(const float* __restrict__ in, unsigned short* __restrict__ out, int n4) {
  int i = blockIdx.x * blockDim.x + threadIdx.x;
  if (i >= n4) return;
  const float4 v = ((const float4*)in)[i];
  u16x4 o;
  o[0] = f32_bf16(v.x); o[1] = f32_bf16(v.y); o[2] = f32_bf16(v.z); o[3] = f32_bf16(v.w);
  ((u16x4*)out)[i] = o;
}

// ---------------- GEMM: C[M][N] = A[M][K] * B[N][K]^T (bf16 in, f32 acc) ----------------
template<int OUTF32>
__global__ __launch_bounds__(256) void gemm_nt(const unsigned short* __restrict__ A,
                                               const unsigned short* __restrict__ B,
                                               void* __restrict__ Cp,
                                               int M, int N, int K) {
  __shared__ unsigned short As[128 * 32];
  __shared__ unsigned short Bs[128 * 32];
  const int t = threadIdx.x;
  const int lane = t & 63;
  const int wave = t >> 6;
  const int wr = (wave >> 1) * 64;
  const int wc = (wave & 1) * 64;
  const long m0 = (long)blockIdx.y * 128;
  const long n0 = (long)blockIdx.x * 128;
  const int l15 = lane & 15, lg = lane >> 4;

  f32x4 acc[4][4];
#pragma unroll
  for (int m = 0; m < 4; ++m)
#pragma unroll
    for (int n = 0; n < 4; ++n) acc[m][n] = (f32x4){0.f, 0.f, 0.f, 0.f};

  const int srow = t >> 2;
  const int scol = (t & 3) * 8;
  const unsigned short* Ag = A + (m0 + srow) * (long)K + scol;
  const unsigned short* Bg = B + (n0 + srow) * (long)K + scol;

  for (int k0 = 0; k0 < K; k0 += 32) {
    gload16(Ag + k0, &As[t * 8]);
    gload16(Ag + (long)64 * K + k0, &As[2048 + t * 8]);
    gload16(Bg + k0, &Bs[t * 8]);
    gload16(Bg + (long)64 * K + k0, &Bs[2048 + t * 8]);
    __syncthreads();
    bf16x8 af[4], bfr[4];
#pragma unroll
    for (int m = 0; m < 4; ++m) af[m] = *(const bf16x8*)&As[(wr + m * 16 + l15) * 32 + lg * 8];
#pragma unroll
    for (int n = 0; n < 4; ++n) bfr[n] = *(const bf16x8*)&Bs[(wc + n * 16 + l15) * 32 + lg * 8];
#pragma unroll
    for (int m = 0; m < 4; ++m)
#pragma unroll
      for (int n = 0; n < 4; ++n)
        acc[m][n] = __builtin_amdgcn_mfma_f32_16x16x32_bf16(af[m], bfr[n], acc[m][n], 0, 0, 0);
    __syncthreads();
  }

#pragma unroll
  for (int m = 0; m < 4; ++m)
#pragma unroll
    for (int n = 0; n < 4; ++n)
#pragma unroll
      for (int r = 0; r < 4; ++r) {
        long row = m0 + wr + m * 16 + lg * 4 + r;
        long col = n0 + wc + n * 16 + l15;
        if (OUTF32)
          ((float*)Cp)[row * N + col] = acc[m][n][r];
        else
          ((unsigned short*)Cp)[row * N + col] = f32_bf16(acc[m][n][r]);
      }
}

// ---------------- RoPE cos/sin table: [b][s][128] f32 ----------------
__global__ void rope_table(const int* __restrict__ pos, float* __restrict__ ctab,
                           float* __restrict__ stab) {
  int i = blockIdx.x * blockDim.x + threadIdx.x;  // 2*2048*128 exact
  int d = i & 127;
  int s = (i >> 7) & 2047;
  int b = i >> 18;
  float p = (float)pos[b * 2048 + s];
  float f = p * exp2f(-(float)d * 0.10381025296523f);
  float sn, c;
  sincosf(f, &sn, &c);
  ctab[i] = c;
  stab[i] = sn;
}

// ---------------- RoPE apply (vectorized, fused qkv layout; h==8 is K) ----------------
__global__ void rope_apply(unsigned short* __restrict__ qkv, const float* __restrict__ ctab,
                           const float* __restrict__ stab) {
  int i = blockIdx.x * blockDim.x + threadIdx.x;  // 2*2048*9*16 exact
  int g = i & 15;
  int hh = (i >> 4) % 9;
  int sb_ = (i >> 4) / 9;
  int s = sb_ & 2047;
  int b = sb_ >> 11;
  size_t base = (size_t)(b * 2048 + s) * 2560 + (hh == 8 ? 2048 : hh * 256) + g * 8;
  const float* ct = ctab + ((size_t)(b * 2048 + s) << 7) + g * 8;
  const float* st = stab + ((size_t)(b * 2048 + s) << 7) + g * 8;
  bf16x8 lo = *(const bf16x8*)(qkv + base);
  bf16x8 hi = *(const bf16x8*)(qkv + base + 128);
  bf16x8 lo2, hi2;
#pragma unroll
  for (int e = 0; e < 8; ++e) {
    float c = ct[e], sn = st[e];
    float x1 = bf16_f32((unsigned short)lo[e]);
    float x2 = bf16_f32((unsigned short)hi[e]);
    lo2[e] = (short)f32_bf16(x1 * c - x2 * sn);
    hi2[e] = (short)f32_bf16(x2 * c + x1 * sn);
  }
  *(bf16x8*)(qkv + base) = lo2;
  *(bf16x8*)(qkv + base + 128) = hi2;
}

// ---------------- V transpose (tiled): vt[b][d][s] = qkv[b][s][2304+d] ----------------
__global__ __launch_bounds__(256) void transpose_v(const unsigned short* __restrict__ qkv,
                                                   unsigned short* __restrict__ vt) {
  __shared__ unsigned short tile[64][68];
  const int t = threadIdx.x;
  const int s0 = blockIdx.x * 64, d0 = blockIdx.y * 64, b = blockIdx.z;
  const int r = t >> 4, c4 = (t & 15) * 4;
#pragma unroll
  for (int j = 0; j < 4; ++j) {
    int row = r + j * 16;
    const unsigned short* src = qkv + (size_t)(b * 2048 + s0 + row) * 2560 + 2304 + d0 + c4;
#pragma unroll
    for (int e = 0; e < 4; ++e) tile[row][c4 + e] = src[e];
  }
  __syncthreads();
#pragma unroll
  for (int j = 0; j < 4; ++j) {
    int drow = r + j * 16;
    u16x4 o;
#pragma unroll
    for (int e = 0; e < 4; ++e) o[e] = tile[c4 + e][drow];
    *(u16x4*)(vt + (size_t)(b * 256 + d0 + drow) * 2048 + s0 + c4) = o;
  }
}

// ---------------- flash attention: swapped QK^T, LDS-staged K/V, dbuf 2-phase ----------------
__global__ __launch_bounds__(256) void attn2(const unsigned short* __restrict__ qkv,
                                             const unsigned short* __restrict__ vt,
                                             unsigned short* __restrict__ O) {
  __shared__ __align__(16) unsigned short Ks[2][32 * 256];  // 32 keys x 256 d, xor-swz (row&7)<<4
  __shared__ __align__(16) unsigned short Vs[2][256 * 32];  // 256 d x 32 keys, xor-swz (row&3)<<4
  const int t = threadIdx.x, lane = t & 63, wave = t >> 6;
  const int l15 = lane & 15, lg = lane >> 4;
  const int qb = blockIdx.x, h = blockIdx.y, b = blockIdx.z;
  const int q0 = qb * 64;
  const int qg = q0 + wave * 16 + l15;  // this lane's q row

  // Q as B-frags: lane holds Q[col=q=l15][k = c*32 + lg*8 + e]
  bf16x8 qf[8];
  {
    const unsigned short* qp = qkv + (size_t)(b * 2048 + qg) * 2560 + h * 256 + lg * 8;
#pragma unroll
    for (int c = 0; c < 8; ++c) qf[c] = *(const bf16x8*)(qp + c * 32);
  }

  // staging address precompute (pre-swizzled global source, linear LDS dest)
  size_t kgb[4], vgb[4];
  int klo[4], vlo[4];
#pragma unroll
  for (int p = 0; p < 4; ++p) {
    int i = p * 256 + t;
    int kr = i >> 5, kb = (i & 31) << 4;
    int ksrc = kb ^ ((kr & 7) << 4);
    kgb[p] = (size_t)(b * 2048 + kr) * 2560 + 2048 + (ksrc >> 1);
    klo[p] = i * 8;
    int vr = i >> 2, vb = (i & 3) << 4;
    int vsrc = vb ^ ((vr & 3) << 4);
    vgb[p] = (size_t)(b * 256 + vr) * 2048 + (vsrc >> 1);
    vlo[p] = i * 8;
  }

  f32x4 oacc[16];
#pragma unroll
  for (int dt = 0; dt < 16; ++dt) oacc[dt] = (f32x4){0.f, 0.f, 0.f, 0.f};
  float mrun = -3e30f, lrun = 0.f;

  int ks0 = q0 - 1023;
  if (ks0 < 0) ks0 = 0;
  ks0 &= ~31;
  const int nst = (q0 + 64 - ks0) >> 5;

  // prologue stage into buf 0
#pragma unroll
  for (int p = 0; p < 4; ++p) gload16(qkv + kgb[p] + (size_t)ks0 * 2560, &Ks[0][klo[p]]);
#pragma unroll
  for (int p = 0; p < 4; ++p) gload16(vt + vgb[p] + ks0, &Vs[0][vlo[p]]);
  __syncthreads();

  for (int si = 0; si < nst; ++si) {
    const int ks = ks0 + si * 32;
    const int cur = si & 1;
    if (si + 1 < nst) {  // issue next-tile stage (uniform branch)
      const size_t ko = (size_t)(ks + 32) * 2560;
#pragma unroll
      for (int p = 0; p < 4; ++p) gload16(qkv + kgb[p] + ko, &Ks[cur ^ 1][klo[p]]);
#pragma unroll
      for (int p = 0; p < 4; ++p) gload16(vt + vgb[p] + (ks + 32), &Vs[cur ^ 1][vlo[p]]);
    }
    const unsigned short* Kc = Ks[cur];
    const unsigned short* Vc = Vs[cur];

    // S^T = K · Q^T : lane holds S[key = n*16 + lg*4 + r][q = l15]
    f32x4 sa = (f32x4){0.f, 0.f, 0.f, 0.f};
    f32x4 sb2 = (f32x4){0.f, 0.f, 0.f, 0.f};
    const int kswz = (l15 & 7) << 4;
#pragma unroll
    for (int c = 0; c < 8; ++c) {
      const int off = ((c * 64 + lg * 16) ^ kswz) >> 1;
      bf16x8 k0 = *(const bf16x8*)&Kc[l15 * 256 + off];
      bf16x8 k1 = *(const bf16x8*)&Kc[(16 + l15) * 256 + off];
      sa = __builtin_amdgcn_mfma_f32_16x16x32_bf16(k0, qf[c], sa, 0, 0, 0);
      sb2 = __builtin_amdgcn_mfma_f32_16x16x32_bf16(k1, qf[c], sb2, 0, 0, 0);
    }

    // mask + online softmax (q = qg per lane; all 4 lg-groups hold same q)
    float pv[8];
    const int kb0 = ks + lg * 4, kb1 = kb0 + 16;
    const int lo_b = qg - 1024;
#pragma unroll
    for (int r = 0; r < 4; ++r) {
      int k0i = kb0 + r, k1i = kb1 + r;
      pv[r] = (k0i <= qg && k0i > lo_b) ? sa[r] * SCALE : -3e38f;
      pv[4 + r] = (k1i <= qg && k1i > lo_b) ? sb2[r] * SCALE : -3e38f;
    }
    float mx = fmaxf(fmaxf(fmaxf(pv[0], pv[1]), fmaxf(pv[2], pv[3])),
                     fmaxf(fmaxf(pv[4], pv[5]), fmaxf(pv[6], pv[7])));
    mx = fmaxf(mx, __shfl_xor(mx, 16));
    mx = fmaxf(mx, __shfl_xor(mx, 32));
    if (!__all(mx - mrun <= 8.0f)) {  // defer-max (T13)
      float mnew = fmaxf(mrun, mx);
      float al = exp2f((mrun - mnew) * LOG2E);
#pragma unroll
      for (int dt = 0; dt < 16; ++dt) oacc[dt] *= al;
      lrun *= al;
      mrun = mnew;
    }
    float ps = 0.f;
#pragma unroll
    for (int j = 0; j < 8; ++j) {
      pv[j] = exp2f((pv[j] - mrun) * LOG2E);
      ps += pv[j];
    }
    ps += __shfl_xor(ps, 16);
    ps += __shfl_xor(ps, 32);
    lrun += ps;

    // pack P to bf16 pairs; w[j] = keys (lg*4+2j', lg*4+2j'+1) of tiles n=0 (w0,w1), n=1 (w2,w3)
    unsigned int w0 = ((unsigned int)f32_bf16(pv[1]) << 16) | f32_bf16(pv[0]);
    unsigned int w1 = ((unsigned int)f32_bf16(pv[3]) << 16) | f32_bf16(pv[2]);
    unsigned int w2 = ((unsigned int)f32_bf16(pv[5]) << 16) | f32_bf16(pv[4]);
    unsigned int w3 = ((unsigned int)f32_bf16(pv[7]) << 16) | f32_bf16(pv[6]);
    // gather into P^T B-frag: lane (l15,lg) needs keys lg*8..lg*8+7 of q=l15
    const int srcA = l15 + ((lg & 1) << 5);
    const int srcB = srcA + 16;
    unsigned int a0 = __shfl((int)w0, srcA), a1 = __shfl((int)w1, srcA);
    unsigned int a2 = __shfl((int)w2, srcA), a3 = __shfl((int)w3, srcA);
    unsigned int b0 = __shfl((int)w0, srcB), b1 = __shfl((int)w1, srcB);
    unsigned int b2 = __shfl((int)w2, srcB), b3 = __shfl((int)w3, srcB);
    union { unsigned int u[4]; bf16x8 v; } pu;
    const bool hi2 = (lg >> 1) != 0;
    pu.u[0] = hi2 ? a2 : a0;
    pu.u[1] = hi2 ? a3 : a1;
    pu.u[2] = hi2 ? b2 : b0;
    pu.u[3] = hi2 ? b3 : b1;

    // PV: O^T[d][q] += V^T-frag (A) * P^T-frag (B)
    const int vswz = (lg * 16) ^ ((l15 & 3) << 4);
#pragma unroll
    for (int dt = 0; dt < 16; ++dt) {
      bf16x8 vf = *(const bf16x8*)&Vc[(dt * 16 + l15) * 32 + (vswz >> 1)];
      oacc[dt] = __builtin_amdgcn_mfma_f32_16x16x32_bf16(vf, pu.v, oacc[dt], 0, 0, 0);
    }
    __syncthreads();  // drains vmcnt (next tile staged) + all waves done reading cur
  }

  // epilogue: lane holds O^T[d = dt*16 + lg*4 + r][q = qg]
  float inv = 1.0f / lrun;
  unsigned short* op = O + (size_t)(b * 2048 + qg) * 2048 + h * 256 + lg * 4;
#pragma unroll
  for (int dt = 0; dt < 16; ++dt) {
    u16x4 o4;
#pragma unroll
    for (int r = 0; r < 4; ++r) o4[r] = f32_bf16(oacc[dt][r] * inv);
    *(u16x4*)(op + dt * 16) = o4;
  }
}

// ---------------- launch ----------------
extern "C" void kernel_launch(void* const* d_in, const int* in_sizes, int n_in,
                              void* d_out, int out_size, void* d_ws, size_t ws_size,
                              hipStream_t stream) {
  const float* hidden = (const float*)d_in[0];
  // d_in[1]: attention_mask (pure causal; handled analytically)
  const int* pos_ids = (const int*)d_in[2];
  const float* Wq = (const float*)d_in[3];
  const float* Wk = (const float*)d_in[4];
  const float* Wv = (const float*)d_in[5];
  const float* Wo = (const float*)d_in[6];
  float* out = (float*)d_out;
  char* ws = (char*)d_ws;

  unsigned short* qkv_bf = (unsigned short*)(ws);              // 20 MB: [4096][2560]
  unsigned short* hid_bf = (unsigned short*)(ws + 20971520);   // 16 MB (reused as attn out)
  unsigned short* w_bf   = (unsigned short*)(ws + 37748736);   // 10 MB (Wq|Wk|Wv, later Wo)
  unsigned short* vtbuf  = (unsigned short*)(ws + 48234496);   // 2 MB [b][256][2048]
  float*          ctab   = (float*)(ws + 50331648);            // 2 MB
  float*          stab   = (float*)(ws + 52428800);            // 2 MB
  unsigned short* attno  = hid_bf;                             // alias: hidden dead after qkv GEMM

  // casts: hidden + fused W_qkv
  cast_kernel<<<8192, 256, 0, stream>>>(hidden, hid_bf, 2097152);
  cast_kernel<<<4096, 256, 0, stream>>>(Wq, w_bf, 1048576);
  cast_kernel<<<512, 256, 0, stream>>>(Wk, w_bf + 4194304, 131072);
  cast_kernel<<<512, 256, 0, stream>>>(Wv, w_bf + 4718592, 131072);

  // fused QKV projection: [4096][2560]
  gemm_nt<0><<<dim3(20, 32), 256, 0, stream>>>(hid_bf, w_bf, qkv_bf, 4096, 2560, 2048);

  // Wo cast (reuses w_bf, dead after qkv gemm)
  cast_kernel<<<4096, 256, 0, stream>>>(Wo, w_bf, 1048576);

  // rope table + apply (heads 0..7 = Q, head 8 = K at col 2048)
  rope_table<<<2048, 256, 0, stream>>>(pos_ids, ctab, stab);
  rope_apply<<<2304, 256, 0, stream>>>(qkv_bf, ctab, stab);

  // V transpose to [b][d][s]
  transpose_v<<<dim3(32, 4, 2), 256, 0, stream>>>(qkv_bf, vtbuf);

  // attention
  attn2<<<dim3(32, 8, 2), 256, 0, stream>>>(qkv_bf, vtbuf, attno);

  // output projection (f32 out)
  gemm_nt<1><<<dim3(16, 32), 256, 0, stream>>>(attno, w_bf, out, 4096, 2048, 2048);
}

// Round 5
// 338.854 us; speedup vs baseline: 1.8323x; 1.0635x over previous
//
#include <hip/hip_runtime.h>
#include <stdint.h>

typedef __attribute__((ext_vector_type(8))) short bf16x8;
typedef __attribute__((ext_vector_type(4))) float f32x4;
typedef __attribute__((ext_vector_type(4))) unsigned short u16x4;

#define LOG2E 1.44269504088896340736f
#define SCALE 0.0625f

__device__ __forceinline__ unsigned short f32_bf16(float f) {
  unsigned int u = __float_as_uint(f);
  u += 0x7fffu + ((u >> 16) & 1u);
  return (unsigned short)(u >> 16);
}
__device__ __forceinline__ float bf16_f32(unsigned short h) {
  return __uint_as_float(((unsigned int)h) << 16);
}

__device__ __forceinline__ void gload16(const unsigned short* g, unsigned short* l) {
  __builtin_amdgcn_global_load_lds((const __attribute__((address_space(1))) void*)g,
                                   (__attribute__((address_space(3))) void*)l, 16, 0, 0);
}

// ---------------- cast f32 -> bf16 (vectorized) ----------------
__global__ void cast_kernel(const float* __restrict__ in, unsigned short* __restrict__ out, int n4) {
  int i = blockIdx.x * blockDim.x + threadIdx.x;
  if (i >= n4) return;
  const float4 v = ((const float4*)in)[i];
  u16x4 o;
  o[0] = f32_bf16(v.x); o[1] = f32_bf16(v.y); o[2] = f32_bf16(v.z); o[3] = f32_bf16(v.w);
  ((u16x4*)out)[i] = o;
}

// ---------------- GEMM: C[M][N] = A[M][K] * B[N][K]^T, 2-phase pipeline + XCD swizzle ----
template<int OUTF32>
__global__ __launch_bounds__(256) void gemm_nt(const unsigned short* __restrict__ A,
                                               const unsigned short* __restrict__ B,
                                               void* __restrict__ Cp,
                                               int M, int N, int K) {
  __shared__ unsigned short As[2][128 * 32];
  __shared__ unsigned short Bs[2][128 * 32];
  const int t = threadIdx.x;
  const int lane = t & 63;
  const int wave = t >> 6;
  const int wr = (wave >> 1) * 64;
  const int wc = (wave & 1) * 64;
  const int l15 = lane & 15, lg = lane >> 4;

  // XCD-aware block swizzle (nwg % 8 == 0 for all our launches)
  const int gx = gridDim.x, gy = gridDim.y;
  int orig = blockIdx.y * gx + blockIdx.x;
  int nwg = gx * gy;
  int wg = orig;
  if ((nwg & 7) == 0) wg = (orig & 7) * (nwg >> 3) + (orig >> 3);
  const int bx = wg / gy, by = wg % gy;  // consecutive wg share B panel
  const long m0 = (long)by * 128;
  const long n0 = (long)bx * 128;

  f32x4 acc[4][4];
#pragma unroll
  for (int m = 0; m < 4; ++m)
#pragma unroll
    for (int n = 0; n < 4; ++n) acc[m][n] = (f32x4){0.f, 0.f, 0.f, 0.f};

  const int srow = t >> 2;
  const int scol = (t & 3) * 8;
  const unsigned short* Ag = A + (m0 + srow) * (long)K + scol;
  const unsigned short* Bg = B + (n0 + srow) * (long)K + scol;

  auto stage = [&](int buf, int k0) {
    gload16(Ag + k0, &As[buf][t * 8]);
    gload16(Ag + (long)64 * K + k0, &As[buf][2048 + t * 8]);
    gload16(Bg + k0, &Bs[buf][t * 8]);
    gload16(Bg + (long)64 * K + k0, &Bs[buf][2048 + t * 8]);
  };

  stage(0, 0);
  __syncthreads();  // drains vmcnt(0): buf0 ready
  int cur = 0;
  for (int k0 = 0; k0 < K; k0 += 32) {
    if (k0 + 32 < K) stage(cur ^ 1, k0 + 32);  // prefetch overlaps compute
    bf16x8 af[4], bfr[4];
#pragma unroll
    for (int m = 0; m < 4; ++m) af[m] = *(const bf16x8*)&As[cur][(wr + m * 16 + l15) * 32 + lg * 8];
#pragma unroll
    for (int n = 0; n < 4; ++n) bfr[n] = *(const bf16x8*)&Bs[cur][(wc + n * 16 + l15) * 32 + lg * 8];
    __builtin_amdgcn_s_setprio(1);
#pragma unroll
    for (int m = 0; m < 4; ++m)
#pragma unroll
      for (int n = 0; n < 4; ++n)
        acc[m][n] = __builtin_amdgcn_mfma_f32_16x16x32_bf16(af[m], bfr[n], acc[m][n], 0, 0, 0);
    __builtin_amdgcn_s_setprio(0);
    __syncthreads();  // one barrier/step: drains prefetch (vmcnt) + all reads of cur done
    cur ^= 1;
  }

#pragma unroll
  for (int m = 0; m < 4; ++m)
#pragma unroll
    for (int n = 0; n < 4; ++n)
#pragma unroll
      for (int r = 0; r < 4; ++r) {
        long row = m0 + wr + m * 16 + lg * 4 + r;
        long col = n0 + wc + n * 16 + l15;
        if (OUTF32)
          ((float*)Cp)[row * N + col] = acc[m][n][r];
        else
          ((unsigned short*)Cp)[row * N + col] = f32_bf16(acc[m][n][r]);
      }
}

// ---------------- RoPE cos/sin table: [b][s][128] f32 ----------------
__global__ void rope_table(const int* __restrict__ pos, float* __restrict__ ctab,
                           float* __restrict__ stab) {
  int i = blockIdx.x * blockDim.x + threadIdx.x;  // 2*2048*128 exact
  int d = i & 127;
  int s = (i >> 7) & 2047;
  int b = i >> 18;
  float p = (float)pos[b * 2048 + s];
  float f = p * exp2f(-(float)d * 0.10381025296523f);
  float sn, c;
  sincosf(f, &sn, &c);
  ctab[i] = c;
  stab[i] = sn;
}

// ---------------- RoPE apply (vectorized, fused qkv layout; h==8 is K) ----------------
__global__ void rope_apply(unsigned short* __restrict__ qkv, const float* __restrict__ ctab,
                           const float* __restrict__ stab) {
  int i = blockIdx.x * blockDim.x + threadIdx.x;  // 2*2048*9*16 exact
  int g = i & 15;
  int hh = (i >> 4) % 9;
  int sb_ = (i >> 4) / 9;
  int s = sb_ & 2047;
  int b = sb_ >> 11;
  size_t base = (size_t)(b * 2048 + s) * 2560 + (hh == 8 ? 2048 : hh * 256) + g * 8;
  const float* ct = ctab + ((size_t)(b * 2048 + s) << 7) + g * 8;
  const float* st = stab + ((size_t)(b * 2048 + s) << 7) + g * 8;
  bf16x8 lo = *(const bf16x8*)(qkv + base);
  bf16x8 hi = *(const bf16x8*)(qkv + base + 128);
  bf16x8 lo2, hi2;
#pragma unroll
  for (int e = 0; e < 8; ++e) {
    float c = ct[e], sn = st[e];
    float x1 = bf16_f32((unsigned short)lo[e]);
    float x2 = bf16_f32((unsigned short)hi[e]);
    lo2[e] = (short)f32_bf16(x1 * c - x2 * sn);
    hi2[e] = (short)f32_bf16(x2 * c + x1 * sn);
  }
  *(bf16x8*)(qkv + base) = lo2;
  *(bf16x8*)(qkv + base + 128) = hi2;
}

// ---------------- V transpose (tiled): vt[b][d][s] = qkv[b][s][2304+d] ----------------
__global__ __launch_bounds__(256) void transpose_v(const unsigned short* __restrict__ qkv,
                                                   unsigned short* __restrict__ vt) {
  __shared__ unsigned short tile[64][68];
  const int t = threadIdx.x;
  const int s0 = blockIdx.x * 64, d0 = blockIdx.y * 64, b = blockIdx.z;
  const int r = t >> 4, c4 = (t & 15) * 4;
#pragma unroll
  for (int j = 0; j < 4; ++j) {
    int row = r + j * 16;
    const unsigned short* src = qkv + (size_t)(b * 2048 + s0 + row) * 2560 + 2304 + d0 + c4;
#pragma unroll
    for (int e = 0; e < 4; ++e) tile[row][c4 + e] = src[e];
  }
  __syncthreads();
#pragma unroll
  for (int j = 0; j < 4; ++j) {
    int drow = r + j * 16;
    u16x4 o;
#pragma unroll
    for (int e = 0; e < 4; ++e) o[e] = tile[c4 + e][drow];
    *(u16x4*)(vt + (size_t)(b * 256 + d0 + drow) * 2048 + s0 + c4) = o;
  }
}

// ---------------- flash attention: swapped QK^T, LDS-staged K/V, dbuf 2-phase ----------------
__global__ __launch_bounds__(256) void attn2(const unsigned short* __restrict__ qkv,
                                             const unsigned short* __restrict__ vt,
                                             unsigned short* __restrict__ O) {
  __shared__ __align__(16) unsigned short Ks[2][32 * 256];  // 32 keys x 256 d, swz (row&7)<<4
  __shared__ __align__(16) unsigned short Vs[2][256 * 32];  // 256 d x 32 keys, swz ((row>>1)&3)<<4
  const int t = threadIdx.x, lane = t & 63, wave = t >> 6;
  const int l15 = lane & 15, lg = lane >> 4;
  const int qb = blockIdx.x, h = blockIdx.y, b = blockIdx.z;
  const int q0 = qb * 64;
  const int qg = q0 + wave * 16 + l15;  // this lane's q row

  // Q as B-frags: lane holds Q[col=q=l15][k = c*32 + lg*8 + e]
  bf16x8 qf[8];
  {
    const unsigned short* qp = qkv + (size_t)(b * 2048 + qg) * 2560 + h * 256 + lg * 8;
#pragma unroll
    for (int c = 0; c < 8; ++c) qf[c] = *(const bf16x8*)(qp + c * 32);
  }

  // staging address precompute (pre-swizzled global source, linear LDS dest)
  size_t kgb[4], vgb[4];
  int klo[4], vlo[4];
#pragma unroll
  for (int p = 0; p < 4; ++p) {
    int i = p * 256 + t;
    int kr = i >> 5, kb = (i & 31) << 4;
    int ksrc = kb ^ ((kr & 7) << 4);
    kgb[p] = (size_t)(b * 2048 + kr) * 2560 + 2048 + (ksrc >> 1);
    klo[p] = i * 8;
    int vr = i >> 2, vb = (i & 3) << 4;
    int vsrc = vb ^ (((vr >> 1) & 3) << 4);  // row bits 1-2: spreads over full 128B bank span
    vgb[p] = (size_t)(b * 256 + vr) * 2048 + (vsrc >> 1);
    vlo[p] = i * 8;
  }

  f32x4 oacc[16];
#pragma unroll
  for (int dt = 0; dt < 16; ++dt) oacc[dt] = (f32x4){0.f, 0.f, 0.f, 0.f};
  float mrun = -3e30f, lrun = 0.f;

  int ks0 = q0 - 1023;
  if (ks0 < 0) ks0 = 0;
  ks0 &= ~31;
  const int nst = (q0 + 64 - ks0) >> 5;

  // prologue stage into buf 0
#pragma unroll
  for (int p = 0; p < 4; ++p) gload16(qkv + kgb[p] + (size_t)ks0 * 2560, &Ks[0][klo[p]]);
#pragma unroll
  for (int p = 0; p < 4; ++p) gload16(vt + vgb[p] + ks0, &Vs[0][vlo[p]]);
  __syncthreads();

  for (int si = 0; si < nst; ++si) {
    const int ks = ks0 + si * 32;
    const int cur = si & 1;
    if (si + 1 < nst) {  // issue next-tile stage (uniform branch)
      const size_t ko = (size_t)(ks + 32) * 2560;
#pragma unroll
      for (int p = 0; p < 4; ++p) gload16(qkv + kgb[p] + ko, &Ks[cur ^ 1][klo[p]]);
#pragma unroll
      for (int p = 0; p < 4; ++p) gload16(vt + vgb[p] + (ks + 32), &Vs[cur ^ 1][vlo[p]]);
    }
    const unsigned short* Kc = Ks[cur];
    const unsigned short* Vc = Vs[cur];

    // S^T = K · Q^T : lane holds S[key = n*16 + lg*4 + r][q = l15]
    f32x4 sa = (f32x4){0.f, 0.f, 0.f, 0.f};
    f32x4 sb2 = (f32x4){0.f, 0.f, 0.f, 0.f};
    const int kswz = (l15 & 7) << 4;
    __builtin_amdgcn_s_setprio(1);
#pragma unroll
    for (int c = 0; c < 8; ++c) {
      const int off = ((c * 64 + lg * 16) ^ kswz) >> 1;
      bf16x8 k0 = *(const bf16x8*)&Kc[l15 * 256 + off];
      bf16x8 k1 = *(const bf16x8*)&Kc[(16 + l15) * 256 + off];
      sa = __builtin_amdgcn_mfma_f32_16x16x32_bf16(k0, qf[c], sa, 0, 0, 0);
      sb2 = __builtin_amdgcn_mfma_f32_16x16x32_bf16(k1, qf[c], sb2, 0, 0, 0);
    }
    __builtin_amdgcn_s_setprio(0);

    // mask + online softmax (q = qg per lane; all 4 lg-groups hold same q)
    float pv[8];
    const int kb0 = ks + lg * 4, kb1 = kb0 + 16;
    const int lo_b = qg - 1024;
#pragma unroll
    for (int r = 0; r < 4; ++r) {
      int k0i = kb0 + r, k1i = kb1 + r;
      pv[r] = (k0i <= qg && k0i > lo_b) ? sa[r] * SCALE : -3e38f;
      pv[4 + r] = (k1i <= qg && k1i > lo_b) ? sb2[r] * SCALE : -3e38f;
    }
    float mx = fmaxf(fmaxf(fmaxf(pv[0], pv[1]), fmaxf(pv[2], pv[3])),
                     fmaxf(fmaxf(pv[4], pv[5]), fmaxf(pv[6], pv[7])));
    mx = fmaxf(mx, __shfl_xor(mx, 16));
    mx = fmaxf(mx, __shfl_xor(mx, 32));
    if (!__all(mx - mrun <= 8.0f)) {  // defer-max (T13)
      float mnew = fmaxf(mrun, mx);
      float al = exp2f((mrun - mnew) * LOG2E);
#pragma unroll
      for (int dt = 0; dt < 16; ++dt) oacc[dt] *= al;
      lrun *= al;
      mrun = mnew;
    }
    float ps = 0.f;
#pragma unroll
    for (int j = 0; j < 8; ++j) {
      pv[j] = exp2f((pv[j] - mrun) * LOG2E);
      ps += pv[j];
    }
    ps += __shfl_xor(ps, 16);
    ps += __shfl_xor(ps, 32);
    lrun += ps;

    // pack P to bf16 pairs: w0,w1 = tile0 keys (lg*4..+3); w2,w3 = tile1
    unsigned int w0 = ((unsigned int)f32_bf16(pv[1]) << 16) | f32_bf16(pv[0]);
    unsigned int w1 = ((unsigned int)f32_bf16(pv[3]) << 16) | f32_bf16(pv[2]);
    unsigned int w2 = ((unsigned int)f32_bf16(pv[5]) << 16) | f32_bf16(pv[4]);
    unsigned int w3 = ((unsigned int)f32_bf16(pv[7]) << 16) | f32_bf16(pv[6]);
    // P^T B-frag redistribution via conflict-free XOR exchanges (lg-crossing only):
    // lane lg needs pairs from sources {a, a+1}, a=(lg&1)*2, of tile (lg>>1).
    unsigned int sA0 = (lg < 2) ? w2 : w0;  // stage A: send opposite-tile pair across xor32
    unsigned int sA1 = (lg < 2) ? w3 : w1;
    unsigned int rA0 = (unsigned int)__shfl_xor((int)sA0, 32);
    unsigned int rA1 = (unsigned int)__shfl_xor((int)sA1, 32);
    unsigned int own0 = (lg < 2) ? w0 : w2;  // own pair of my tile
    unsigned int own1 = (lg < 2) ? w1 : w3;
    const bool sendOwn = ((lg ^ (lg >> 1)) & 1) != 0;  // stage B: send across xor16
    unsigned int sB0 = sendOwn ? own0 : rA0;
    unsigned int sB1 = sendOwn ? own1 : rA1;
    unsigned int rB0 = (unsigned int)__shfl_xor((int)sB0, 16);
    unsigned int rB1 = (unsigned int)__shfl_xor((int)sB1, 16);
    union { unsigned int u[4]; bf16x8 v; } pu;
    pu.u[0] = (lg == 0) ? own0 : ((lg == 2) ? rA0 : rB0);
    pu.u[1] = (lg == 0) ? own1 : ((lg == 2) ? rA1 : rB1);
    pu.u[2] = (lg == 3) ? own0 : ((lg == 1) ? rA0 : rB0);
    pu.u[3] = (lg == 3) ? own1 : ((lg == 1) ? rA1 : rB1);

    // PV: O^T[d][q] += V^T-frag (A) * P^T-frag (B)
    const int vswz = (lg * 16) ^ (((l15 >> 1) & 3) << 4);
    __builtin_amdgcn_s_setprio(1);
#pragma unroll
    for (int dt = 0; dt < 16; ++dt) {
      bf16x8 vf = *(const bf16x8*)&Vc[(dt * 16 + l15) * 32 + (vswz >> 1)];
      oacc[dt] = __builtin_amdgcn_mfma_f32_16x16x32_bf16(vf, pu.v, oacc[dt], 0, 0, 0);
    }
    __builtin_amdgcn_s_setprio(0);
    __syncthreads();  // drains vmcnt (next tile staged) + all waves done reading cur
  }

  // epilogue: lane holds O^T[d = dt*16 + lg*4 + r][q = qg]
  float inv = 1.0f / lrun;
  unsigned short* op = O + (size_t)(b * 2048 + qg) * 2048 + h * 256 + lg * 4;
#pragma unroll
  for (int dt = 0; dt < 16; ++dt) {
    u16x4 o4;
#pragma unroll
    for (int r = 0; r < 4; ++r) o4[r] = f32_bf16(oacc[dt][r] * inv);
    *(u16x4*)(op + dt * 16) = o4;
  }
}

// ---------------- launch ----------------
extern "C" void kernel_launch(void* const* d_in, const int* in_sizes, int n_in,
                              void* d_out, int out_size, void* d_ws, size_t ws_size,
                              hipStream_t stream) {
  const float* hidden = (const float*)d_in[0];
  // d_in[1]: attention_mask (pure causal; handled analytically)
  const int* pos_ids = (const int*)d_in[2];
  const float* Wq = (const float*)d_in[3];
  const float* Wk = (const float*)d_in[4];
  const float* Wv = (const float*)d_in[5];
  const float* Wo = (const float*)d_in[6];
  float* out = (float*)d_out;
  char* ws = (char*)d_ws;

  unsigned short* qkv_bf = (unsigned short*)(ws);              // 20 MB: [4096][2560]
  unsigned short* hid_bf = (unsigned short*)(ws + 20971520);   // 16 MB (reused as attn out)
  unsigned short* w_bf   = (unsigned short*)(ws + 37748736);   // 10 MB (Wq|Wk|Wv, later Wo)
  unsigned short* vtbuf  = (unsigned short*)(ws + 48234496);   // 2 MB [b][256][2048]
  float*          ctab   = (float*)(ws + 50331648);            // 2 MB
  float*          stab   = (float*)(ws + 52428800);            // 2 MB
  unsigned short* attno  = hid_bf;                             // alias: hidden dead after qkv GEMM

  // casts: hidden + fused W_qkv
  cast_kernel<<<8192, 256, 0, stream>>>(hidden, hid_bf, 2097152);
  cast_kernel<<<4096, 256, 0, stream>>>(Wq, w_bf, 1048576);
  cast_kernel<<<512, 256, 0, stream>>>(Wk, w_bf + 4194304, 131072);
  cast_kernel<<<512, 256, 0, stream>>>(Wv, w_bf + 4718592, 131072);

  // fused QKV projection: [4096][2560]  (grid 20x32 = 640 blocks, %8==0)
  gemm_nt<0><<<dim3(20, 32), 256, 0, stream>>>(hid_bf, w_bf, qkv_bf, 4096, 2560, 2048);

  // Wo cast (reuses w_bf, dead after qkv gemm)
  cast_kernel<<<4096, 256, 0, stream>>>(Wo, w_bf, 1048576);

  // rope table + apply (heads 0..7 = Q, head 8 = K at col 2048)
  rope_table<<<2048, 256, 0, stream>>>(pos_ids, ctab, stab);
  rope_apply<<<2304, 256, 0, stream>>>(qkv_bf, ctab, stab);

  // V transpose to [b][d][s]
  transpose_v<<<dim3(32, 4, 2), 256, 0, stream>>>(qkv_bf, vtbuf);

  // attention
  attn2<<<dim3(32, 8, 2), 256, 0, stream>>>(qkv_bf, vtbuf, attno);

  // output projection (f32 out; grid 16x32 = 512 blocks, %8==0)
  gemm_nt<1><<<dim3(16, 32), 256, 0, stream>>>(attno, w_bf, out, 4096, 2048, 2048);
}